// Round 2
// baseline (5300.496 us; speedup 1.0000x reference)
//
#include <hip/hip_runtime.h>
#include <stdint.h>

#define NN 50000
#define NE 600000
#define ND 128
#define NH 512
#define NO 128
#define MPAD 50048  // 391 * 128

typedef unsigned short u16;
typedef __attribute__((ext_vector_type(8))) short bf16x8;
typedef __attribute__((ext_vector_type(4))) float f32x4;

__device__ __forceinline__ u16 f2bf(float f) {
  union { float f; uint32_t u; } v; v.f = f;
  uint32_t u = v.u;
  uint32_t r = (u + 0x7fffu + ((u >> 16) & 1u)) >> 16;
  return (u16)r;
}
__device__ __forceinline__ float bf2f(u16 h) {
  union { uint32_t u; float f; } v; v.u = ((uint32_t)h) << 16; return v.f;
}
__device__ __forceinline__ float4 bfq2f4(uint64_t q) {
  float4 r;
  r.x = bf2f((u16)(q       ));
  r.y = bf2f((u16)(q >> 16));
  r.z = bf2f((u16)(q >> 32));
  r.w = bf2f((u16)(q >> 48));
  return r;
}
__device__ __forceinline__ uint64_t f42bfq(float4 v) {
  union { u16 u[4]; uint64_t q; } o;
  o.u[0] = f2bf(v.x); o.u[1] = f2bf(v.y); o.u[2] = f2bf(v.z); o.u[3] = f2bf(v.w);
  return o.q;
}

__device__ __forceinline__ void gld16(const u16* g, u16* l) {
  __builtin_amdgcn_global_load_lds(
      (const __attribute__((address_space(1))) void*)g,
      (__attribute__((address_space(3))) void*)l, 16, 0, 0);
}

// ---------------------------------------------------------------------------
// GEMM: C[M,512] = A[M,K](bf16) @ B^T   B stored transposed [512,K], hi+lo
// EPI 0: relu -> bf16 store ; EPI 1: plain -> bf16 store ;
// EPI 2: relu -> guarded column-sum atomicAdd into sumOut[512]
// ---------------------------------------------------------------------------
template<int K, int EPI>
__global__ __launch_bounds__(256) void gemm_bt(
    const u16* __restrict__ A, const u16* __restrict__ Bhi,
    const u16* __restrict__ Blo, const float* __restrict__ bias,
    u16* __restrict__ outB, float* __restrict__ sumOut)
{
  __shared__ u16 As[128 * 64];
  __shared__ u16 BsH[128 * 64];
  __shared__ u16 BsL[128 * 64];
  const int tid  = threadIdx.x;
  const int w    = tid >> 6;
  const int lane = tid & 63;
  const int m0   = blockIdx.x * 128;
  const int n0   = blockIdx.y * 128;
  const int wm   = (w >> 1) * 64;
  const int wn   = (w & 1) * 64;
  const int l15  = lane & 15;
  const int lh   = lane >> 4;

  const f32x4 z4 = {0.f, 0.f, 0.f, 0.f};
  f32x4 acc[4][4];
#pragma unroll
  for (int m = 0; m < 4; ++m)
#pragma unroll
    for (int n = 0; n < 4; ++n) acc[m][n] = z4;

  for (int k0 = 0; k0 < K; k0 += 64) {
#pragma unroll
    for (int i = 0; i < 4; ++i) {
      const int cc  = i * 256 + w * 64 + lane;     // 16B chunk id, lane-contig
      const int row = cc >> 3;
      const int c8  = (cc & 7) * 8;
      const int ldsbase = (i * 256 + w * 64) * 8;  // u16 units, wave-uniform
      gld16(A   + (size_t)(m0 + row) * K + k0 + c8, As  + ldsbase);
      gld16(Bhi + (size_t)(n0 + row) * K + k0 + c8, BsH + ldsbase);
      gld16(Blo + (size_t)(n0 + row) * K + k0 + c8, BsL + ldsbase);
    }
    __syncthreads();
#pragma unroll
    for (int ks = 0; ks < 2; ++ks) {
      bf16x8 a[4], bh[4], bl[4];
#pragma unroll
      for (int m = 0; m < 4; ++m)
        a[m] = *(const bf16x8*)&As[(wm + m * 16 + l15) * 64 + ks * 32 + lh * 8];
#pragma unroll
      for (int n = 0; n < 4; ++n) {
        const int o = (wn + n * 16 + l15) * 64 + ks * 32 + lh * 8;
        bh[n] = *(const bf16x8*)&BsH[o];
        bl[n] = *(const bf16x8*)&BsL[o];
      }
#pragma unroll
      for (int m = 0; m < 4; ++m)
#pragma unroll
        for (int n = 0; n < 4; ++n) {
          acc[m][n] = __builtin_amdgcn_mfma_f32_16x16x32_bf16(a[m], bh[n], acc[m][n], 0, 0, 0);
          acc[m][n] = __builtin_amdgcn_mfma_f32_16x16x32_bf16(a[m], bl[n], acc[m][n], 0, 0, 0);
        }
    }
    __syncthreads();
  }

  if (EPI == 2) {
#pragma unroll
    for (int n = 0; n < 4; ++n) {
      const int gc = n0 + wn + n * 16 + l15;
      const float bv = bias[gc];
      float p = 0.f;
#pragma unroll
      for (int m = 0; m < 4; ++m) {
        const int rbase = m0 + wm + m * 16 + lh * 4;
#pragma unroll
        for (int j = 0; j < 4; ++j) {
          if (rbase + j < NN) p += fmaxf(acc[m][n][j] + bv, 0.f);
        }
      }
      p += __shfl_xor(p, 16);
      p += __shfl_xor(p, 32);
      if (lane < 16) atomicAdd(&sumOut[gc], p);
    }
  } else {
#pragma unroll
    for (int m = 0; m < 4; ++m) {
#pragma unroll
      for (int j = 0; j < 4; ++j) {
        const int gr = m0 + wm + m * 16 + lh * 4 + j;
#pragma unroll
        for (int n = 0; n < 4; ++n) {
          const int gc = n0 + wn + n * 16 + l15;
          const float v = acc[m][n][j] + bias[gc];
          outB[(size_t)gr * NH + gc] = f2bf(EPI == 0 ? fmaxf(v, 0.f) : v);
        }
      }
    }
  }
}

// f32 weight [Kd,Nd] -> transposed bf16 hi/lo [Nd,Kd]
__global__ void cvtWT(const float* __restrict__ W, u16* __restrict__ Thi,
                      u16* __restrict__ Tlo, int Kd, int Nd) {
  int t = blockIdx.x * 256 + threadIdx.x;
  if (t >= Kd * Nd) return;
  int k = t / Nd, n = t - k * Nd;
  float wv = W[t];
  u16 hi = f2bf(wv);
  float lo = wv - bf2f(hi);
  Thi[n * Kd + k] = hi;
  Tlo[n * Kd + k] = f2bf(lo);
}

// agg = x for valid rows, 0 for pad rows (dim 128, float4 granularity)
__global__ void init_pad_copy(const float4* __restrict__ x4, float4* __restrict__ a4) {
  int t = blockIdx.x * 256 + threadIdx.x;
  if (t >= MPAD * (ND / 4)) return;
  int row = t / (ND / 4);
  const float4 z = {0.f, 0.f, 0.f, 0.f};
  a4[t] = (row < NN) ? x4[t] : z;
}

// conv1: agg[dst] += x[src], dim=128 f32, float4/thread
__global__ void scatter_x(const int* __restrict__ ei, const float* __restrict__ x,
                          float* __restrict__ agg) {
  int t = blockIdx.x * 256 + threadIdx.x;
  int e = t >> 5;
  int c = (t & 31) << 2;
  int s = ei[e];
  int d = ei[NE + e];
  const float4 v = *(const float4*)(x + (size_t)s * ND + c);
  float* p = agg + (size_t)d * ND + c;
  atomicAdd(p + 0, v.x);
  atomicAdd(p + 1, v.y);
  atomicAdd(p + 2, v.z);
  atomicAdd(p + 3, v.w);
}

__global__ void cvt_bf16(const float4* __restrict__ in, u16* __restrict__ out, int n4) {
  int t = blockIdx.x * 256 + threadIdx.x;
  if (t >= n4) return;
  *(uint64_t*)(out + (size_t)t * 4) = f42bfq(in[t]);
}

// conv2 aggregation, 256-column chunk starting at C0:
// ph[row][0:256] = f32(H[row][C0:C0+256])
__global__ void init_half(const u16* __restrict__ H, float* __restrict__ ph, int C0) {
  int t = blockIdx.x * 256 + threadIdx.x;
  if (t >= MPAD * 64) return;
  int row = t >> 6;
  int c4 = (t & 63) << 2;
  uint64_t q = *(const uint64_t*)(H + (size_t)row * NH + C0 + c4);
  *(float4*)(ph + (size_t)row * 256 + c4) = bfq2f4(q);
}

// ph[dst][c] += f32(H[src][C0+c])
__global__ void scatter_half(const int* __restrict__ ei, const u16* __restrict__ H,
                             float* __restrict__ ph, int C0) {
  int t = blockIdx.x * 256 + threadIdx.x;
  int e = t >> 6;
  int c4 = (t & 63) << 2;
  int s = ei[e];
  int d = ei[NE + e];
  uint64_t q = *(const uint64_t*)(H + (size_t)s * NH + C0 + c4);
  float4 v = bfq2f4(q);
  float* p = ph + (size_t)d * 256 + c4;
  atomicAdd(p + 0, v.x);
  atomicAdd(p + 1, v.y);
  atomicAdd(p + 2, v.z);
  atomicAdd(p + 3, v.w);
}

// R[row][C0+c] = bf16(ph[row][c])
__global__ void cvt_half(const float* __restrict__ ph, u16* __restrict__ R, int C0) {
  int t = blockIdx.x * 256 + threadIdx.x;
  if (t >= MPAD * 64) return;
  int row = t >> 6;
  int c4 = (t & 63) << 2;
  float4 v = *(const float4*)(ph + (size_t)row * 256 + c4);
  *(uint64_t*)(R + (size_t)row * NH + C0 + c4) = f42bfq(v);
}

// out[128] = ((s/NN) @ W2b + b2b) @ Wf + bf   (all f32)
__global__ void final_fuse(const float* __restrict__ s, const float* __restrict__ W2b,
                           const float* __restrict__ b2b, const float* __restrict__ Wf,
                           const float* __restrict__ bfv, float* __restrict__ out) {
  __shared__ float pooled[NH];
  const int j = threadIdx.x;
  const float invN = 1.0f / (float)NN;
  float acc = b2b[j];
  for (int k = 0; k < NH; ++k) acc += s[k] * invN * W2b[k * NH + j];
  pooled[j] = acc;
  __syncthreads();
  if (j < NO) {
    float o = bfv[j];
    for (int k = 0; k < NH; ++k) o += pooled[k] * Wf[k * NO + j];
    out[j] = o;
  }
}

__global__ void ws_sentinel(float* out) {
  if (threadIdx.x < NO) out[threadIdx.x] = -12345.0f;
}

extern "C" void kernel_launch(void* const* d_in, const int* in_sizes, int n_in,
                              void* d_out, int out_size, void* d_ws, size_t ws_size,
                              hipStream_t stream) {
  const float* x   = (const float*)d_in[0];
  const int*   ei  = (const int*)d_in[1];
  const float* W1a = (const float*)d_in[2];
  const float* b1a = (const float*)d_in[3];
  const float* W1b = (const float*)d_in[4];
  const float* b1b = (const float*)d_in[5];
  const float* W2a = (const float*)d_in[6];
  const float* b2a = (const float*)d_in[7];
  const float* W2b = (const float*)d_in[8];
  const float* b2b = (const float*)d_in[9];
  const float* Wf  = (const float*)d_in[10];
  const float* bfv = (const float*)d_in[11];
  float* out = (float*)d_out;

  const size_t PB = (size_t)MPAD * 256 * 4;  // 51.25 MB f32 scratch (agg1+hb1, then ph)
  const size_t RB = (size_t)MPAD * NH * 2;   // 51.25 MB bf16 (r1 then r2)
  const size_t HB = (size_t)MPAD * NH * 2;   // 51.25 MB bf16 (h1)
  const size_t WB = 2 * (size_t)NH * ND * 2 + 4 * (size_t)NH * NH * 2 + 4096;
  if (ws_size < PB + RB + HB + WB + 8 * 256) {
    ws_sentinel<<<1, 128, 0, stream>>>(out);
    return;
  }

  char* ws = (char*)d_ws;
  size_t off = 0;
  auto take = [&](size_t bytes) {
    char* p = ws + off;
    off = (off + bytes + 255) & ~(size_t)255;
    return p;
  };
  float* P  = (float*)take(PB);
  u16*   R  = (u16*)take(RB);
  u16*   H  = (u16*)take(HB);
  u16* W1aT_hi = (u16*)take((size_t)NH * ND * 2);
  u16* W1aT_lo = (u16*)take((size_t)NH * ND * 2);
  u16* W1bT_hi = (u16*)take((size_t)NH * NH * 2);
  u16* W1bT_lo = (u16*)take((size_t)NH * NH * 2);
  u16* W2aT_hi = (u16*)take((size_t)NH * NH * 2);
  u16* W2aT_lo = (u16*)take((size_t)NH * NH * 2);
  float* svec  = (float*)take((size_t)NH * 4);
  u16* hb1 = (u16*)((char*)P + (size_t)MPAD * ND * 4);  // inside P, after agg1 region

  hipMemsetAsync(svec, 0, NH * 4, stream);
  cvtWT<<<(ND * NH + 255) / 256, 256, 0, stream>>>(W1a, W1aT_hi, W1aT_lo, ND, NH);
  cvtWT<<<(NH * NH + 255) / 256, 256, 0, stream>>>(W1b, W1bT_hi, W1bT_lo, NH, NH);
  cvtWT<<<(NH * NH + 255) / 256, 256, 0, stream>>>(W2a, W2aT_hi, W2aT_lo, NH, NH);

  // conv1 aggregation: P[0:MPAD*128] = x (pad 0), += x[src] -> dst
  init_pad_copy<<<(MPAD * (ND / 4) + 255) / 256, 256, 0, stream>>>((const float4*)x, (float4*)P);
  scatter_x<<<NE * 32 / 256, 256, 0, stream>>>(ei, x, P);
  cvt_bf16<<<(MPAD * ND / 4 + 255) / 256, 256, 0, stream>>>((const float4*)P, hb1, MPAD * ND / 4);

  // conv1 MLP: r1 = relu(agg @ W1a + b1a); h1 = r1 @ W1b + b1b (bf16)
  gemm_bt<ND, 0><<<dim3(MPAD / 128, NH / 128), 256, 0, stream>>>(hb1, W1aT_hi, W1aT_lo, b1a, R, nullptr);
  gemm_bt<NH, 1><<<dim3(MPAD / 128, NH / 128), 256, 0, stream>>>(R, W1bT_hi, W1bT_lo, b1b, H, nullptr);

  // conv2 aggregation in two 256-column chunks: r2 = bf16(h1 + seg_sum(h1[src]))
  for (int C0 = 0; C0 < NH; C0 += 256) {
    init_half<<<(MPAD * 64 + 255) / 256, 256, 0, stream>>>(H, P, C0);
    scatter_half<<<NE * 64 / 256, 256, 0, stream>>>(ei, H, P, C0);
    cvt_half<<<(MPAD * 64 + 255) / 256, 256, 0, stream>>>(P, R, C0);
  }

  // conv2 first layer + fused relu + mean-pool partial sums (W2b folded out)
  gemm_bt<NH, 2><<<dim3(MPAD / 128, NH / 128), 256, 0, stream>>>(R, W2aT_hi, W2aT_lo, b2a, nullptr, svec);

  // pooled @ W2b + b2b then @ Wf + bf
  final_fuse<<<1, NH, 0, stream>>>(svec, W2b, b2b, Wf, bfv, out);
}

// Round 3
// 555.265 us; speedup vs baseline: 9.5459x; 9.5459x over previous
//
#include <hip/hip_runtime.h>
#include <stdint.h>

#define NN 50000
#define NE 600000
#define ND 128
#define NH 512
#define NO 128
#define MPAD 50048  // 391 * 128

typedef unsigned short u16;
typedef __attribute__((ext_vector_type(8))) short bf16x8;
typedef __attribute__((ext_vector_type(4))) float f32x4;

__device__ __forceinline__ u16 f2bf(float f) {
  union { float f; uint32_t u; } v; v.f = f;
  uint32_t u = v.u;
  uint32_t r = (u + 0x7fffu + ((u >> 16) & 1u)) >> 16;
  return (u16)r;
}
__device__ __forceinline__ float bf2f(u16 h) {
  union { uint32_t u; float f; } v; v.u = ((uint32_t)h) << 16; return v.f;
}

__device__ __forceinline__ void gld16(const u16* g, u16* l) {
  __builtin_amdgcn_global_load_lds(
      (const __attribute__((address_space(1))) void*)g,
      (__attribute__((address_space(3))) void*)l, 16, 0, 0);
}

// ---------------------------------------------------------------------------
// GEMM: C[M,512] = A[M,K](bf16) @ B^T   B stored transposed [512,K], hi+lo
// EPI 0: relu -> bf16 store ; EPI 1: plain -> bf16 store ;
// EPI 2: relu -> guarded column-sum atomicAdd into sumOut[512]
// ---------------------------------------------------------------------------
template<int K, int EPI>
__global__ __launch_bounds__(256) void gemm_bt(
    const u16* __restrict__ A, const u16* __restrict__ Bhi,
    const u16* __restrict__ Blo, const float* __restrict__ bias,
    u16* __restrict__ outB, float* __restrict__ sumOut)
{
  __shared__ u16 As[128 * 64];
  __shared__ u16 BsH[128 * 64];
  __shared__ u16 BsL[128 * 64];
  const int tid  = threadIdx.x;
  const int w    = tid >> 6;
  const int lane = tid & 63;
  const int m0   = blockIdx.x * 128;
  const int n0   = blockIdx.y * 128;
  const int wm   = (w >> 1) * 64;
  const int wn   = (w & 1) * 64;
  const int l15  = lane & 15;
  const int lh   = lane >> 4;

  const f32x4 z4 = {0.f, 0.f, 0.f, 0.f};
  f32x4 acc[4][4];
#pragma unroll
  for (int m = 0; m < 4; ++m)
#pragma unroll
    for (int n = 0; n < 4; ++n) acc[m][n] = z4;

  for (int k0 = 0; k0 < K; k0 += 64) {
#pragma unroll
    for (int i = 0; i < 4; ++i) {
      const int cc  = i * 256 + w * 64 + lane;     // 16B chunk id, lane-contig
      const int row = cc >> 3;
      const int c8  = (cc & 7) * 8;
      const int ldsbase = (i * 256 + w * 64) * 8;  // u16 units, wave-uniform
      gld16(A   + (size_t)(m0 + row) * K + k0 + c8, As  + ldsbase);
      gld16(Bhi + (size_t)(n0 + row) * K + k0 + c8, BsH + ldsbase);
      gld16(Blo + (size_t)(n0 + row) * K + k0 + c8, BsL + ldsbase);
    }
    __syncthreads();
#pragma unroll
    for (int ks = 0; ks < 2; ++ks) {
      bf16x8 a[4], bh[4], bl[4];
#pragma unroll
      for (int m = 0; m < 4; ++m)
        a[m] = *(const bf16x8*)&As[(wm + m * 16 + l15) * 64 + ks * 32 + lh * 8];
#pragma unroll
      for (int n = 0; n < 4; ++n) {
        const int o = (wn + n * 16 + l15) * 64 + ks * 32 + lh * 8;
        bh[n] = *(const bf16x8*)&BsH[o];
        bl[n] = *(const bf16x8*)&BsL[o];
      }
#pragma unroll
      for (int m = 0; m < 4; ++m)
#pragma unroll
        for (int n = 0; n < 4; ++n) {
          acc[m][n] = __builtin_amdgcn_mfma_f32_16x16x32_bf16(a[m], bh[n], acc[m][n], 0, 0, 0);
          acc[m][n] = __builtin_amdgcn_mfma_f32_16x16x32_bf16(a[m], bl[n], acc[m][n], 0, 0, 0);
        }
    }
    __syncthreads();
  }

  if (EPI == 2) {
#pragma unroll
    for (int n = 0; n < 4; ++n) {
      const int gc = n0 + wn + n * 16 + l15;
      const float bv = bias[gc];
      float p = 0.f;
#pragma unroll
      for (int m = 0; m < 4; ++m) {
        const int rbase = m0 + wm + m * 16 + lh * 4;
#pragma unroll
        for (int j = 0; j < 4; ++j) {
          if (rbase + j < NN) p += fmaxf(acc[m][n][j] + bv, 0.f);
        }
      }
      p += __shfl_xor(p, 16);
      p += __shfl_xor(p, 32);
      if (lane < 16) atomicAdd(&sumOut[gc], p);
    }
  } else {
#pragma unroll
    for (int m = 0; m < 4; ++m) {
#pragma unroll
      for (int j = 0; j < 4; ++j) {
        const int gr = m0 + wm + m * 16 + lh * 4 + j;
#pragma unroll
        for (int n = 0; n < 4; ++n) {
          const int gc = n0 + wn + n * 16 + l15;
          const float v = acc[m][n][j] + bias[gc];
          outB[(size_t)gr * NH + gc] = f2bf(EPI == 0 ? fmaxf(v, 0.f) : v);
        }
      }
    }
  }
}

// f32 weight [Kd,Nd] -> transposed bf16 hi/lo [Nd,Kd]
__global__ void cvtWT(const float* __restrict__ W, u16* __restrict__ Thi,
                      u16* __restrict__ Tlo, int Kd, int Nd) {
  int t = blockIdx.x * 256 + threadIdx.x;
  if (t >= Kd * Nd) return;
  int k = t / Nd, n = t - k * Nd;
  float wv = W[t];
  u16 hi = f2bf(wv);
  float lo = wv - bf2f(hi);
  Thi[n * Kd + k] = hi;
  Tlo[n * Kd + k] = f2bf(lo);
}

// ---------------- CSR construction ----------------
__global__ void zero_int(int* __restrict__ p, int n) {
  int t = blockIdx.x * 256 + threadIdx.x;
  if (t < n) p[t] = 0;
}

__global__ void hist_dst(const int* __restrict__ ei, int* __restrict__ deg) {
  int e = blockIdx.x * 256 + threadIdx.x;
  if (e < NE) atomicAdd(&deg[ei[NE + e]], 1);
}

// single-block exclusive scan of deg[NN] -> rowptr[NN+1], cursor[NN]
__global__ __launch_bounds__(1024) void scan_deg(const int* __restrict__ deg,
                                                 int* __restrict__ rowptr,
                                                 int* __restrict__ cursor) {
  __shared__ int part[1024];
  const int t = threadIdx.x;
  const int chunk = (NN + 1023) / 1024;
  const int lo = t * chunk;
  const int hi = min(lo + chunk, NN);
  int s = 0;
  for (int i = lo; i < hi; ++i) s += deg[i];
  part[t] = s;
  __syncthreads();
  for (int off = 1; off < 1024; off <<= 1) {
    int u = (t >= off) ? part[t - off] : 0;
    __syncthreads();
    part[t] += u;
    __syncthreads();
  }
  int run = part[t] - s;  // exclusive prefix at chunk start
  for (int i = lo; i < hi; ++i) {
    rowptr[i] = run;
    cursor[i] = run;
    run += deg[i];
  }
  if (t == 1023) rowptr[NN] = part[1023];
}

__global__ void fill_csr(const int* __restrict__ ei, int* __restrict__ cursor,
                         int* __restrict__ csr) {
  int e = blockIdx.x * 256 + threadIdx.x;
  if (e >= NE) return;
  int d = ei[NE + e];
  int p = atomicAdd(&cursor[d], 1);
  csr[p] = ei[e];
}

// ---------------- gather-reduce aggregations ----------------
// conv1: hb1[i][:] = bf16( x[i][:] + sum_{e in row i} x[csr[e]][:] )
// one wave per node, lane owns 2 of 128 f32 columns
__global__ __launch_bounds__(256) void gather_x(
    const float* __restrict__ x, const int* __restrict__ rowptr,
    const int* __restrict__ csr, u16* __restrict__ hb1) {
  const int wid  = blockIdx.x * 4 + (threadIdx.x >> 6);
  const int lane = threadIdx.x & 63;
  if (wid >= MPAD) return;
  float a0 = 0.f, a1 = 0.f;
  if (wid < NN) {
    float2 v = *(const float2*)(x + (size_t)wid * ND + lane * 2);
    a0 = v.x; a1 = v.y;
    const int beg = rowptr[wid], end = rowptr[wid + 1];
    int e = beg;
    for (; e + 1 < end; e += 2) {
      int s0 = csr[e], s1 = csr[e + 1];
      float2 v0 = *(const float2*)(x + (size_t)s0 * ND + lane * 2);
      float2 v1 = *(const float2*)(x + (size_t)s1 * ND + lane * 2);
      a0 += v0.x + v1.x;
      a1 += v0.y + v1.y;
    }
    if (e < end) {
      int s0 = csr[e];
      float2 v0 = *(const float2*)(x + (size_t)s0 * ND + lane * 2);
      a0 += v0.x; a1 += v0.y;
    }
  }
  uint32_t o = (uint32_t)f2bf(a0) | ((uint32_t)f2bf(a1) << 16);
  *(uint32_t*)(hb1 + (size_t)wid * ND + lane * 2) = o;
}

// conv2: r2[i][:] = bf16( H[i][:] + sum_{e in row i} H[csr[e]][:] )  (H bf16, dim 512)
// one wave per node, lane owns 8 of 512 bf16 columns (16B/lane -> 1KB/row/wave)
__global__ __launch_bounds__(256) void gather_h(
    const u16* __restrict__ H, const int* __restrict__ rowptr,
    const int* __restrict__ csr, u16* __restrict__ r2) {
  const int wid  = blockIdx.x * 4 + (threadIdx.x >> 6);
  const int lane = threadIdx.x & 63;
  if (wid >= MPAD) return;
  float acc[8];
#pragma unroll
  for (int j = 0; j < 8; ++j) acc[j] = 0.f;
  if (wid < NN) {
    bf16x8 v = *(const bf16x8*)(H + (size_t)wid * NH + lane * 8);
#pragma unroll
    for (int j = 0; j < 8; ++j) acc[j] = bf2f((u16)v[j]);
    const int beg = rowptr[wid], end = rowptr[wid + 1];
    int e = beg;
    for (; e + 1 < end; e += 2) {
      int s0 = csr[e], s1 = csr[e + 1];
      bf16x8 v0 = *(const bf16x8*)(H + (size_t)s0 * NH + lane * 8);
      bf16x8 v1 = *(const bf16x8*)(H + (size_t)s1 * NH + lane * 8);
#pragma unroll
      for (int j = 0; j < 8; ++j) acc[j] += bf2f((u16)v0[j]) + bf2f((u16)v1[j]);
    }
    if (e < end) {
      int s0 = csr[e];
      bf16x8 v0 = *(const bf16x8*)(H + (size_t)s0 * NH + lane * 8);
#pragma unroll
      for (int j = 0; j < 8; ++j) acc[j] += bf2f((u16)v0[j]);
    }
  }
  union { u16 u[8]; uint4 q; } o;
#pragma unroll
  for (int j = 0; j < 8; ++j) o.u[j] = f2bf(acc[j]);
  *(uint4*)(r2 + (size_t)wid * NH + lane * 8) = o.q;
}

// out[128] = ((s/NN) @ W2b + b2b) @ Wf + bf   (all f32)
__global__ void final_fuse(const float* __restrict__ s, const float* __restrict__ W2b,
                           const float* __restrict__ b2b, const float* __restrict__ Wf,
                           const float* __restrict__ bfv, float* __restrict__ out) {
  __shared__ float pooled[NH];
  const int j = threadIdx.x;
  const float invN = 1.0f / (float)NN;
  float acc = b2b[j];
  for (int k = 0; k < NH; ++k) acc += s[k] * invN * W2b[k * NH + j];
  pooled[j] = acc;
  __syncthreads();
  if (j < NO) {
    float o = bfv[j];
    for (int k = 0; k < NH; ++k) o += pooled[k] * Wf[k * NO + j];
    out[j] = o;
  }
}

__global__ void ws_sentinel(float* out) {
  if (threadIdx.x < NO) out[threadIdx.x] = -12345.0f;
}

extern "C" void kernel_launch(void* const* d_in, const int* in_sizes, int n_in,
                              void* d_out, int out_size, void* d_ws, size_t ws_size,
                              hipStream_t stream) {
  const float* x   = (const float*)d_in[0];
  const int*   ei  = (const int*)d_in[1];
  const float* W1a = (const float*)d_in[2];
  const float* b1a = (const float*)d_in[3];
  const float* W1b = (const float*)d_in[4];
  const float* b1b = (const float*)d_in[5];
  const float* W2a = (const float*)d_in[6];
  const float* b2a = (const float*)d_in[7];
  const float* W2b = (const float*)d_in[8];
  const float* b2b = (const float*)d_in[9];
  const float* Wf  = (const float*)d_in[10];
  const float* bfv = (const float*)d_in[11];
  float* out = (float*)d_out;

  const size_t HB1 = (size_t)MPAD * ND * 2;  // 12.8 MB bf16
  const size_t RB  = (size_t)MPAD * NH * 2;  // 51.25 MB bf16 (r1, then r2)
  const size_t HB  = (size_t)MPAD * NH * 2;  // 51.25 MB bf16 (h1)
  const size_t WB  = 2 * (size_t)NH * ND * 2 + 4 * (size_t)NH * NH * 2;
  const size_t CSRB = (size_t)(NN + 1) * 4 + 2 * (size_t)NN * 4 + (size_t)NE * 4;
  const size_t NEED = HB1 + RB + HB + WB + CSRB + NH * 4 + 16 * 256;
  if (ws_size < NEED) {
    ws_sentinel<<<1, 128, 0, stream>>>(out);
    return;
  }

  char* ws = (char*)d_ws;
  size_t off = 0;
  auto take = [&](size_t bytes) {
    char* p = ws + off;
    off = (off + bytes + 255) & ~(size_t)255;
    return p;
  };
  u16* hb1 = (u16*)take(HB1);
  u16* R   = (u16*)take(RB);
  u16* H   = (u16*)take(HB);
  u16* W1aT_hi = (u16*)take((size_t)NH * ND * 2);
  u16* W1aT_lo = (u16*)take((size_t)NH * ND * 2);
  u16* W1bT_hi = (u16*)take((size_t)NH * NH * 2);
  u16* W1bT_lo = (u16*)take((size_t)NH * NH * 2);
  u16* W2aT_hi = (u16*)take((size_t)NH * NH * 2);
  u16* W2aT_lo = (u16*)take((size_t)NH * NH * 2);
  int* deg    = (int*)take((size_t)NN * 4);
  int* cursor = (int*)take((size_t)NN * 4);
  int* rowptr = (int*)take((size_t)(NN + 1) * 4);
  int* csr    = (int*)take((size_t)NE * 4);
  float* svec = (float*)take((size_t)NH * 4);

  hipMemsetAsync(svec, 0, NH * 4, stream);

  // weights -> transposed bf16 hi/lo
  cvtWT<<<(ND * NH + 255) / 256, 256, 0, stream>>>(W1a, W1aT_hi, W1aT_lo, ND, NH);
  cvtWT<<<(NH * NH + 255) / 256, 256, 0, stream>>>(W1b, W1bT_hi, W1bT_lo, NH, NH);
  cvtWT<<<(NH * NH + 255) / 256, 256, 0, stream>>>(W2a, W2aT_hi, W2aT_lo, NH, NH);

  // CSR: deg -> rowptr/cursor -> csr (src sorted by dst)
  zero_int<<<(NN + 255) / 256, 256, 0, stream>>>(deg, NN);
  hist_dst<<<(NE + 255) / 256, 256, 0, stream>>>(ei, deg);
  scan_deg<<<1, 1024, 0, stream>>>(deg, rowptr, cursor);
  fill_csr<<<(NE + 255) / 256, 256, 0, stream>>>(ei, cursor, csr);

  // conv1: gather + MLP
  gather_x<<<(MPAD + 3) / 4, 256, 0, stream>>>(x, rowptr, csr, hb1);
  gemm_bt<ND, 0><<<dim3(MPAD / 128, NH / 128), 256, 0, stream>>>(hb1, W1aT_hi, W1aT_lo, b1a, R, nullptr);
  gemm_bt<NH, 1><<<dim3(MPAD / 128, NH / 128), 256, 0, stream>>>(R, W1bT_hi, W1bT_lo, b1b, H, nullptr);

  // conv2: gather (r2 overwrites R) + first layer fused with relu+mean-pool
  gather_h<<<(MPAD + 3) / 4, 256, 0, stream>>>(H, rowptr, csr, R);
  gemm_bt<NH, 2><<<dim3(MPAD / 128, NH / 128), 256, 0, stream>>>(R, W2aT_hi, W2aT_lo, b2a, nullptr, svec);

  // pooled @ W2b + b2b then @ Wf + bf
  final_fuse<<<1, NH, 0, stream>>>(svec, W2b, b2b, Wf, bfv, out);
}

// Round 4
// 458.119 us; speedup vs baseline: 11.5701x; 1.2121x over previous
//
#include <hip/hip_runtime.h>
#include <stdint.h>

#define NN 50000
#define NE 600000
#define ND 128
#define NH 512
#define NO 128
#define MPAD 50048  // 391 * 128
#define NB 196      // ceil(NN/256) scan blocks

typedef unsigned short u16;
typedef __attribute__((ext_vector_type(8))) short bf16x8;
typedef __attribute__((ext_vector_type(4))) float f32x4;

__device__ __forceinline__ u16 f2bf(float f) {
  union { float f; uint32_t u; } v; v.f = f;
  uint32_t u = v.u;
  uint32_t r = (u + 0x7fffu + ((u >> 16) & 1u)) >> 16;
  return (u16)r;
}
__device__ __forceinline__ float bf2f(u16 h) {
  union { uint32_t u; float f; } v; v.u = ((uint32_t)h) << 16; return v.f;
}

__device__ __forceinline__ void gld16(const u16* g, u16* l) {
  __builtin_amdgcn_global_load_lds(
      (const __attribute__((address_space(1))) void*)g,
      (__attribute__((address_space(3))) void*)l, 16, 0, 0);
}

// ---------------------------------------------------------------------------
// GEMM: C[M,512] = A[M,K](bf16) @ B^T   B stored transposed [512,K], hi+lo
// EPI 0: relu -> bf16 store ; EPI 1: plain -> bf16 store ;
// EPI 2: relu -> guarded column-sum atomicAdd into sumOut[512]
// ---------------------------------------------------------------------------
template<int K, int EPI>
__global__ __launch_bounds__(256) void gemm_bt(
    const u16* __restrict__ A, const u16* __restrict__ Bhi,
    const u16* __restrict__ Blo, const float* __restrict__ bias,
    u16* __restrict__ outB, float* __restrict__ sumOut)
{
  __shared__ u16 As[128 * 64];
  __shared__ u16 BsH[128 * 64];
  __shared__ u16 BsL[128 * 64];
  const int tid  = threadIdx.x;
  const int w    = tid >> 6;
  const int lane = tid & 63;
  const int m0   = blockIdx.x * 128;
  const int n0   = blockIdx.y * 128;
  const int wm   = (w >> 1) * 64;
  const int wn   = (w & 1) * 64;
  const int l15  = lane & 15;
  const int lh   = lane >> 4;

  const f32x4 z4 = {0.f, 0.f, 0.f, 0.f};
  f32x4 acc[4][4];
#pragma unroll
  for (int m = 0; m < 4; ++m)
#pragma unroll
    for (int n = 0; n < 4; ++n) acc[m][n] = z4;

  for (int k0 = 0; k0 < K; k0 += 64) {
#pragma unroll
    for (int i = 0; i < 4; ++i) {
      const int cc  = i * 256 + w * 64 + lane;     // 16B chunk id, lane-contig
      const int row = cc >> 3;
      const int c8  = (cc & 7) * 8;
      const int ldsbase = (i * 256 + w * 64) * 8;  // u16 units, wave-uniform
      gld16(A   + (size_t)(m0 + row) * K + k0 + c8, As  + ldsbase);
      gld16(Bhi + (size_t)(n0 + row) * K + k0 + c8, BsH + ldsbase);
      gld16(Blo + (size_t)(n0 + row) * K + k0 + c8, BsL + ldsbase);
    }
    __syncthreads();
#pragma unroll
    for (int ks = 0; ks < 2; ++ks) {
      bf16x8 a[4], bh[4], bl[4];
#pragma unroll
      for (int m = 0; m < 4; ++m)
        a[m] = *(const bf16x8*)&As[(wm + m * 16 + l15) * 64 + ks * 32 + lh * 8];
#pragma unroll
      for (int n = 0; n < 4; ++n) {
        const int o = (wn + n * 16 + l15) * 64 + ks * 32 + lh * 8;
        bh[n] = *(const bf16x8*)&BsH[o];
        bl[n] = *(const bf16x8*)&BsL[o];
      }
#pragma unroll
      for (int m = 0; m < 4; ++m)
#pragma unroll
        for (int n = 0; n < 4; ++n) {
          acc[m][n] = __builtin_amdgcn_mfma_f32_16x16x32_bf16(a[m], bh[n], acc[m][n], 0, 0, 0);
          acc[m][n] = __builtin_amdgcn_mfma_f32_16x16x32_bf16(a[m], bl[n], acc[m][n], 0, 0, 0);
        }
    }
    __syncthreads();
  }

  if (EPI == 2) {
#pragma unroll
    for (int n = 0; n < 4; ++n) {
      const int gc = n0 + wn + n * 16 + l15;
      const float bv = bias[gc];
      float p = 0.f;
#pragma unroll
      for (int m = 0; m < 4; ++m) {
        const int rbase = m0 + wm + m * 16 + lh * 4;
#pragma unroll
        for (int j = 0; j < 4; ++j) {
          if (rbase + j < NN) p += fmaxf(acc[m][n][j] + bv, 0.f);
        }
      }
      p += __shfl_xor(p, 16);
      p += __shfl_xor(p, 32);
      if (lane < 16) atomicAdd(&sumOut[gc], p);
    }
  } else {
#pragma unroll
    for (int m = 0; m < 4; ++m) {
#pragma unroll
      for (int j = 0; j < 4; ++j) {
        const int gr = m0 + wm + m * 16 + lh * 4 + j;
#pragma unroll
        for (int n = 0; n < 4; ++n) {
          const int gc = n0 + wn + n * 16 + l15;
          const float v = acc[m][n][j] + bias[gc];
          outB[(size_t)gr * NH + gc] = f2bf(EPI == 0 ? fmaxf(v, 0.f) : v);
        }
      }
    }
  }
}

// f32 weight [Kd,Nd] -> transposed bf16 hi/lo [Nd,Kd]
__global__ void cvtWT(const float* __restrict__ W, u16* __restrict__ Thi,
                      u16* __restrict__ Tlo, int Kd, int Nd) {
  int t = blockIdx.x * 256 + threadIdx.x;
  if (t >= Kd * Nd) return;
  int k = t / Nd, n = t - k * Nd;
  float wv = W[t];
  u16 hi = f2bf(wv);
  float lo = wv - bf2f(hi);
  Thi[n * Kd + k] = hi;
  Tlo[n * Kd + k] = f2bf(lo);
}

// ---------------- CSR construction ----------------
__global__ void hist_dst(const int* __restrict__ ei, int* __restrict__ deg) {
  int e = blockIdx.x * 256 + threadIdx.x;
  if (e < NE) atomicAdd(&deg[ei[NE + e]], 1);
}

// per-block sums of deg (256 elements per block)
__global__ void deg_partial(const int* __restrict__ deg, int* __restrict__ bsum) {
  const int i = blockIdx.x * 256 + threadIdx.x;
  int v = (i < NN) ? deg[i] : 0;
#pragma unroll
  for (int o = 1; o < 64; o <<= 1) v += __shfl_xor(v, o);
  __shared__ int ws[4];
  if ((threadIdx.x & 63) == 0) ws[threadIdx.x >> 6] = v;
  __syncthreads();
  if (threadIdx.x == 0) bsum[blockIdx.x] = ws[0] + ws[1] + ws[2] + ws[3];
}

// single-block exclusive scan of bsum[NB] -> boff[NB]; also rowptr[NN] = NE
__global__ void scan_bsum(const int* __restrict__ bsum, int* __restrict__ boff,
                          int* __restrict__ rowptr) {
  __shared__ int s[256];
  const int t = threadIdx.x;
  int v = (t < NB) ? bsum[t] : 0;
  s[t] = v;
  __syncthreads();
  for (int o = 1; o < 256; o <<= 1) {
    int u = (t >= o) ? s[t - o] : 0;
    __syncthreads();
    s[t] += u;
    __syncthreads();
  }
  if (t < NB) boff[t] = s[t] - v;
  if (t == 0) rowptr[NN] = NE;
}

// per-block exclusive scan + block offset -> rowptr, cursor
__global__ void scan_apply(const int* __restrict__ deg, const int* __restrict__ boff,
                           int* __restrict__ rowptr, int* __restrict__ cursor) {
  __shared__ int s[256];
  const int t = threadIdx.x;
  const int i = blockIdx.x * 256 + t;
  int v = (i < NN) ? deg[i] : 0;
  s[t] = v;
  __syncthreads();
  for (int o = 1; o < 256; o <<= 1) {
    int u = (t >= o) ? s[t - o] : 0;
    __syncthreads();
    s[t] += u;
    __syncthreads();
  }
  if (i < NN) {
    int ex = boff[blockIdx.x] + s[t] - v;
    rowptr[i] = ex;
    cursor[i] = ex;
  }
}

__global__ void fill_csr(const int* __restrict__ ei, int* __restrict__ cursor,
                         int* __restrict__ csr) {
  int e = blockIdx.x * 256 + threadIdx.x;
  if (e >= NE) return;
  int d = ei[NE + e];
  int p = atomicAdd(&cursor[d], 1);
  csr[p] = ei[e];
}

// ---------------- gather-reduce aggregations ----------------
// conv1: hb1[i][:] = bf16( x[i][:] + sum_{e in row i} x[csr[e]][:] )
__global__ __launch_bounds__(256) void gather_x(
    const float* __restrict__ x, const int* __restrict__ rowptr,
    const int* __restrict__ csr, u16* __restrict__ hb1) {
  const int wid  = blockIdx.x * 4 + (threadIdx.x >> 6);
  const int lane = threadIdx.x & 63;
  if (wid >= MPAD) return;
  float a0 = 0.f, a1 = 0.f;
  if (wid < NN) {
    float2 v = *(const float2*)(x + (size_t)wid * ND + lane * 2);
    a0 = v.x; a1 = v.y;
    const int beg = rowptr[wid], end = rowptr[wid + 1];
    int e = beg;
    for (; e + 1 < end; e += 2) {
      int s0 = csr[e], s1 = csr[e + 1];
      float2 v0 = *(const float2*)(x + (size_t)s0 * ND + lane * 2);
      float2 v1 = *(const float2*)(x + (size_t)s1 * ND + lane * 2);
      a0 += v0.x + v1.x;
      a1 += v0.y + v1.y;
    }
    if (e < end) {
      int s0 = csr[e];
      float2 v0 = *(const float2*)(x + (size_t)s0 * ND + lane * 2);
      a0 += v0.x; a1 += v0.y;
    }
  }
  uint32_t o = (uint32_t)f2bf(a0) | ((uint32_t)f2bf(a1) << 16);
  *(uint32_t*)(hb1 + (size_t)wid * ND + lane * 2) = o;
}

// conv2: r2[i][:] = bf16( H[i][:] + sum_{e in row i} H[csr[e]][:] )  (H bf16, dim 512)
__global__ __launch_bounds__(256) void gather_h(
    const u16* __restrict__ H, const int* __restrict__ rowptr,
    const int* __restrict__ csr, u16* __restrict__ r2) {
  const int wid  = blockIdx.x * 4 + (threadIdx.x >> 6);
  const int lane = threadIdx.x & 63;
  if (wid >= MPAD) return;
  float acc[8];
#pragma unroll
  for (int j = 0; j < 8; ++j) acc[j] = 0.f;
  if (wid < NN) {
    bf16x8 v = *(const bf16x8*)(H + (size_t)wid * NH + lane * 8);
#pragma unroll
    for (int j = 0; j < 8; ++j) acc[j] = bf2f((u16)v[j]);
    const int beg = rowptr[wid], end = rowptr[wid + 1];
    int e = beg;
    for (; e + 1 < end; e += 2) {
      int s0 = csr[e], s1 = csr[e + 1];
      bf16x8 v0 = *(const bf16x8*)(H + (size_t)s0 * NH + lane * 8);
      bf16x8 v1 = *(const bf16x8*)(H + (size_t)s1 * NH + lane * 8);
#pragma unroll
      for (int j = 0; j < 8; ++j) acc[j] += bf2f((u16)v0[j]) + bf2f((u16)v1[j]);
    }
    if (e < end) {
      int s0 = csr[e];
      bf16x8 v0 = *(const bf16x8*)(H + (size_t)s0 * NH + lane * 8);
#pragma unroll
      for (int j = 0; j < 8; ++j) acc[j] += bf2f((u16)v0[j]);
    }
  }
  union { u16 u[8]; uint4 q; } o;
#pragma unroll
  for (int j = 0; j < 8; ++j) o.u[j] = f2bf(acc[j]);
  *(uint4*)(r2 + (size_t)wid * NH + lane * 8) = o.q;
}

// out[128] = ((s/NN) @ W2b + b2b) @ Wf + bf   (all f32)
__global__ void final_fuse(const float* __restrict__ s, const float* __restrict__ W2b,
                           const float* __restrict__ b2b, const float* __restrict__ Wf,
                           const float* __restrict__ bfv, float* __restrict__ out) {
  __shared__ float pooled[NH];
  const int j = threadIdx.x;
  const float invN = 1.0f / (float)NN;
  float acc = b2b[j];
  for (int k = 0; k < NH; ++k) acc += s[k] * invN * W2b[k * NH + j];
  pooled[j] = acc;
  __syncthreads();
  if (j < NO) {
    float o = bfv[j];
    for (int k = 0; k < NH; ++k) o += pooled[k] * Wf[k * NO + j];
    out[j] = o;
  }
}

__global__ void ws_sentinel(float* out) {
  if (threadIdx.x < NO) out[threadIdx.x] = -12345.0f;
}

extern "C" void kernel_launch(void* const* d_in, const int* in_sizes, int n_in,
                              void* d_out, int out_size, void* d_ws, size_t ws_size,
                              hipStream_t stream) {
  const float* x   = (const float*)d_in[0];
  const int*   ei  = (const int*)d_in[1];
  const float* W1a = (const float*)d_in[2];
  const float* b1a = (const float*)d_in[3];
  const float* W1b = (const float*)d_in[4];
  const float* b1b = (const float*)d_in[5];
  const float* W2a = (const float*)d_in[6];
  const float* b2a = (const float*)d_in[7];
  const float* W2b = (const float*)d_in[8];
  const float* b2b = (const float*)d_in[9];
  const float* Wf  = (const float*)d_in[10];
  const float* bfv = (const float*)d_in[11];
  float* out = (float*)d_out;

  const size_t HB1 = (size_t)MPAD * ND * 2;  // 12.8 MB bf16
  const size_t RB  = (size_t)MPAD * NH * 2;  // 51.25 MB bf16 (r1, then r2)
  const size_t HB  = (size_t)MPAD * NH * 2;  // 51.25 MB bf16 (h1)
  const size_t WB  = 2 * (size_t)NH * ND * 2 + 4 * (size_t)NH * NH * 2;
  const size_t CSRB = (size_t)(NN + 1) * 4 + 2 * (size_t)NN * 4 + (size_t)NE * 4
                      + 2 * (size_t)NB * 4;
  const size_t NEED = HB1 + RB + HB + WB + CSRB + NH * 4 + 32 * 256;
  if (ws_size < NEED) {
    ws_sentinel<<<1, 128, 0, stream>>>(out);
    return;
  }

  char* ws = (char*)d_ws;
  size_t off = 0;
  auto take = [&](size_t bytes) {
    char* p = ws + off;
    off = (off + bytes + 255) & ~(size_t)255;
    return p;
  };
  u16* hb1 = (u16*)take(HB1);
  u16* R   = (u16*)take(RB);
  u16* H   = (u16*)take(HB);
  u16* W1aT_hi = (u16*)take((size_t)NH * ND * 2);
  u16* W1aT_lo = (u16*)take((size_t)NH * ND * 2);
  u16* W1bT_hi = (u16*)take((size_t)NH * NH * 2);
  u16* W1bT_lo = (u16*)take((size_t)NH * NH * 2);
  u16* W2aT_hi = (u16*)take((size_t)NH * NH * 2);
  u16* W2aT_lo = (u16*)take((size_t)NH * NH * 2);
  int* deg    = (int*)take((size_t)NN * 4);
  int* cursor = (int*)take((size_t)NN * 4);
  int* rowptr = (int*)take((size_t)(NN + 1) * 4);
  int* csr    = (int*)take((size_t)NE * 4);
  int* bsum   = (int*)take((size_t)NB * 4);
  int* boff   = (int*)take((size_t)NB * 4);
  float* svec = (float*)take((size_t)NH * 4);

  hipMemsetAsync(svec, 0, NH * 4, stream);
  hipMemsetAsync(deg, 0, (size_t)NN * 4, stream);

  // weights -> transposed bf16 hi/lo
  cvtWT<<<(ND * NH + 255) / 256, 256, 0, stream>>>(W1a, W1aT_hi, W1aT_lo, ND, NH);
  cvtWT<<<(NH * NH + 255) / 256, 256, 0, stream>>>(W1b, W1bT_hi, W1bT_lo, NH, NH);
  cvtWT<<<(NH * NH + 255) / 256, 256, 0, stream>>>(W2a, W2aT_hi, W2aT_lo, NH, NH);

  // CSR: deg -> parallel exclusive scan -> rowptr/cursor -> csr
  hist_dst<<<(NE + 255) / 256, 256, 0, stream>>>(ei, deg);
  deg_partial<<<NB, 256, 0, stream>>>(deg, bsum);
  scan_bsum<<<1, 256, 0, stream>>>(bsum, boff, rowptr);
  scan_apply<<<NB, 256, 0, stream>>>(deg, boff, rowptr, cursor);
  fill_csr<<<(NE + 255) / 256, 256, 0, stream>>>(ei, cursor, csr);

  // conv1: gather + MLP
  gather_x<<<(MPAD + 3) / 4, 256, 0, stream>>>(x, rowptr, csr, hb1);
  gemm_bt<ND, 0><<<dim3(MPAD / 128, NH / 128), 256, 0, stream>>>(hb1, W1aT_hi, W1aT_lo, b1a, R, nullptr);
  gemm_bt<NH, 1><<<dim3(MPAD / 128, NH / 128), 256, 0, stream>>>(R, W1bT_hi, W1bT_lo, b1b, H, nullptr);

  // conv2: gather (r2 overwrites R) + first layer fused with relu+mean-pool
  gather_h<<<(MPAD + 3) / 4, 256, 0, stream>>>(H, rowptr, csr, R);
  gemm_bt<NH, 2><<<dim3(MPAD / 128, NH / 128), 256, 0, stream>>>(R, W2aT_hi, W2aT_lo, b2a, nullptr, svec);

  // pooled @ W2b + b2b then @ Wf + bf
  final_fuse<<<1, NH, 0, stream>>>(svec, W2b, b2b, Wf, bfv, out);
}

// Round 5
// 406.526 us; speedup vs baseline: 13.0385x; 1.1269x over previous
//
#include <hip/hip_runtime.h>
#include <stdint.h>

#define NN 50000
#define NE 600000
#define ND 128
#define NH 512
#define NO 128
#define MPAD 50048  // 391 * 128
#define NB 196      // ceil(NN/256) scan blocks

typedef unsigned short u16;
typedef __attribute__((ext_vector_type(8))) short bf16x8;
typedef __attribute__((ext_vector_type(4))) float f32x4;

__device__ __forceinline__ u16 f2bf(float f) {
  union { float f; uint32_t u; } v; v.f = f;
  uint32_t u = v.u;
  uint32_t r = (u + 0x7fffu + ((u >> 16) & 1u)) >> 16;
  return (u16)r;
}
__device__ __forceinline__ float bf2f(u16 h) {
  union { uint32_t u; float f; } v; v.u = ((uint32_t)h) << 16; return v.f;
}

__device__ __forceinline__ void gld16(const u16* g, u16* l) {
  __builtin_amdgcn_global_load_lds(
      (const __attribute__((address_space(1))) void*)g,
      (__attribute__((address_space(3))) void*)l, 16, 0, 0);
}

// ---------------------------------------------------------------------------
// GEMM: C[M,512] = A[M,K](bf16) @ B^T   B stored transposed [512,K], hi+lo
// 1-D grid 1564, bijective XCD remap, m=wgid>>2 n=wgid&3 (A-tile L2 reuse).
// LDS tiles XOR-swizzled: linear LDS dest (global_load_lds), pre-swizzled
// global source chunk, same XOR on the ds_read side (rule #21).
// EPI 0: relu -> bf16 store ; EPI 1: plain -> bf16 store ;
// EPI 2: relu -> guarded column-sum atomicAdd into sumOut[512]
// ---------------------------------------------------------------------------
template<int K, int EPI>
__global__ __launch_bounds__(256) void gemm_bt(
    const u16* __restrict__ A, const u16* __restrict__ Bhi,
    const u16* __restrict__ Blo, const float* __restrict__ bias,
    u16* __restrict__ outB, float* __restrict__ sumOut)
{
  __shared__ u16 As[128 * 64];
  __shared__ u16 BsH[128 * 64];
  __shared__ u16 BsL[128 * 64];
  // bijective XCD-chunk remap (nwg = 1564, q=195, r=4) then m/n decompose
  const int nwg  = gridDim.x;
  const int q    = nwg >> 3, r = nwg & 7;
  const int xcd  = blockIdx.x & 7, loc = blockIdx.x >> 3;
  const int wgid = (xcd < r ? xcd * (q + 1) : r * (q + 1) + (xcd - r) * q) + loc;
  const int m0   = (wgid >> 2) * 128;
  const int n0   = (wgid & 3) * 128;

  const int tid  = threadIdx.x;
  const int w    = tid >> 6;
  const int lane = tid & 63;
  const int wm   = (w >> 1) * 64;
  const int wn   = (w & 1) * 64;
  const int l15  = lane & 15;
  const int lh   = lane >> 4;

  const f32x4 z4 = {0.f, 0.f, 0.f, 0.f};
  f32x4 acc[4][4];
#pragma unroll
  for (int m = 0; m < 4; ++m)
#pragma unroll
    for (int n = 0; n < 4; ++n) acc[m][n] = z4;

  for (int k0 = 0; k0 < K; k0 += 64) {
#pragma unroll
    for (int i = 0; i < 4; ++i) {
      const int cc  = i * 256 + w * 64 + lane;     // 16B chunk id, lane-contig
      const int row = cc >> 3;
      const int csw = (cc ^ row) & 7;              // swizzled source chunk
      const int ldsbase = (i * 256 + w * 64) * 8;  // u16 units, wave-uniform (linear)
      gld16(A   + (size_t)(m0 + row) * K + k0 + csw * 8, As  + ldsbase);
      gld16(Bhi + (size_t)(n0 + row) * K + k0 + csw * 8, BsH + ldsbase);
      gld16(Blo + (size_t)(n0 + row) * K + k0 + csw * 8, BsL + ldsbase);
    }
    __syncthreads();
#pragma unroll
    for (int ks = 0; ks < 2; ++ks) {
      bf16x8 a[4], bh[4], bl[4];
#pragma unroll
      for (int m = 0; m < 4; ++m) {
        const int row = wm + m * 16 + l15;
        const int ch  = (ks * 4 + lh) ^ (row & 7);
        a[m] = *(const bf16x8*)&As[row * 64 + ch * 8];
      }
#pragma unroll
      for (int n = 0; n < 4; ++n) {
        const int row = wn + n * 16 + l15;
        const int ch  = (ks * 4 + lh) ^ (row & 7);
        bh[n] = *(const bf16x8*)&BsH[row * 64 + ch * 8];
        bl[n] = *(const bf16x8*)&BsL[row * 64 + ch * 8];
      }
#pragma unroll
      for (int m = 0; m < 4; ++m)
#pragma unroll
        for (int n = 0; n < 4; ++n) {
          acc[m][n] = __builtin_amdgcn_mfma_f32_16x16x32_bf16(a[m], bh[n], acc[m][n], 0, 0, 0);
          acc[m][n] = __builtin_amdgcn_mfma_f32_16x16x32_bf16(a[m], bl[n], acc[m][n], 0, 0, 0);
        }
    }
    __syncthreads();
  }

  if (EPI == 2) {
#pragma unroll
    for (int n = 0; n < 4; ++n) {
      const int gc = n0 + wn + n * 16 + l15;
      const float bv = bias[gc];
      float p = 0.f;
#pragma unroll
      for (int m = 0; m < 4; ++m) {
        const int rbase = m0 + wm + m * 16 + lh * 4;
#pragma unroll
        for (int j = 0; j < 4; ++j) {
          if (rbase + j < NN) p += fmaxf(acc[m][n][j] + bv, 0.f);
        }
      }
      p += __shfl_xor(p, 16);
      p += __shfl_xor(p, 32);
      if (lane < 16) atomicAdd(&sumOut[gc], p);
    }
  } else {
#pragma unroll
    for (int m = 0; m < 4; ++m) {
#pragma unroll
      for (int j = 0; j < 4; ++j) {
        const int gr = m0 + wm + m * 16 + lh * 4 + j;
#pragma unroll
        for (int n = 0; n < 4; ++n) {
          const int gc = n0 + wn + n * 16 + l15;
          const float v = acc[m][n][j] + bias[gc];
          outB[(size_t)gr * NH + gc] = f2bf(EPI == 0 ? fmaxf(v, 0.f) : v);
        }
      }
    }
  }
}

// f32 weight [Kd,Nd] -> transposed bf16 hi/lo [Nd,Kd]
__global__ void cvtWT(const float* __restrict__ W, u16* __restrict__ Thi,
                      u16* __restrict__ Tlo, int Kd, int Nd) {
  int t = blockIdx.x * 256 + threadIdx.x;
  if (t >= Kd * Nd) return;
  int k = t / Nd, n = t - k * Nd;
  float wv = W[t];
  u16 hi = f2bf(wv);
  float lo = wv - bf2f(hi);
  Thi[n * Kd + k] = hi;
  Tlo[n * Kd + k] = f2bf(lo);
}

// ---------------- CSR construction ----------------
__global__ void hist_dst(const int* __restrict__ ei, int* __restrict__ deg) {
  int e = blockIdx.x * 256 + threadIdx.x;
  if (e < NE) atomicAdd(&deg[ei[NE + e]], 1);
}

__global__ void deg_partial(const int* __restrict__ deg, int* __restrict__ bsum) {
  const int i = blockIdx.x * 256 + threadIdx.x;
  int v = (i < NN) ? deg[i] : 0;
#pragma unroll
  for (int o = 1; o < 64; o <<= 1) v += __shfl_xor(v, o);
  __shared__ int ws[4];
  if ((threadIdx.x & 63) == 0) ws[threadIdx.x >> 6] = v;
  __syncthreads();
  if (threadIdx.x == 0) bsum[blockIdx.x] = ws[0] + ws[1] + ws[2] + ws[3];
}

__global__ void scan_bsum(const int* __restrict__ bsum, int* __restrict__ boff,
                          int* __restrict__ rowptr) {
  __shared__ int s[256];
  const int t = threadIdx.x;
  int v = (t < NB) ? bsum[t] : 0;
  s[t] = v;
  __syncthreads();
  for (int o = 1; o < 256; o <<= 1) {
    int u = (t >= o) ? s[t - o] : 0;
    __syncthreads();
    s[t] += u;
    __syncthreads();
  }
  if (t < NB) boff[t] = s[t] - v;
  if (t == 0) rowptr[NN] = NE;
}

__global__ void scan_apply(const int* __restrict__ deg, const int* __restrict__ boff,
                           int* __restrict__ rowptr, int* __restrict__ cursor) {
  __shared__ int s[256];
  const int t = threadIdx.x;
  const int i = blockIdx.x * 256 + t;
  int v = (i < NN) ? deg[i] : 0;
  s[t] = v;
  __syncthreads();
  for (int o = 1; o < 256; o <<= 1) {
    int u = (t >= o) ? s[t - o] : 0;
    __syncthreads();
    s[t] += u;
    __syncthreads();
  }
  if (i < NN) {
    int ex = boff[blockIdx.x] + s[t] - v;
    rowptr[i] = ex;
    cursor[i] = ex;
  }
}

__global__ void fill_csr(const int* __restrict__ ei, int* __restrict__ cursor,
                         int* __restrict__ csr) {
  int e = blockIdx.x * 256 + threadIdx.x;
  if (e >= NE) return;
  int d = ei[NE + e];
  int p = atomicAdd(&cursor[d], 1);
  csr[p] = ei[e];
}

// ---------------- gather-reduce aggregations ----------------
__global__ __launch_bounds__(256) void gather_x(
    const float* __restrict__ x, const int* __restrict__ rowptr,
    const int* __restrict__ csr, u16* __restrict__ hb1) {
  const int wid  = blockIdx.x * 4 + (threadIdx.x >> 6);
  const int lane = threadIdx.x & 63;
  if (wid >= MPAD) return;
  float a0 = 0.f, a1 = 0.f;
  if (wid < NN) {
    float2 v = *(const float2*)(x + (size_t)wid * ND + lane * 2);
    a0 = v.x; a1 = v.y;
    const int beg = rowptr[wid], end = rowptr[wid + 1];
    int e = beg;
    for (; e + 1 < end; e += 2) {
      int s0 = csr[e], s1 = csr[e + 1];
      float2 v0 = *(const float2*)(x + (size_t)s0 * ND + lane * 2);
      float2 v1 = *(const float2*)(x + (size_t)s1 * ND + lane * 2);
      a0 += v0.x + v1.x;
      a1 += v0.y + v1.y;
    }
    if (e < end) {
      int s0 = csr[e];
      float2 v0 = *(const float2*)(x + (size_t)s0 * ND + lane * 2);
      a0 += v0.x; a1 += v0.y;
    }
  }
  uint32_t o = (uint32_t)f2bf(a0) | ((uint32_t)f2bf(a1) << 16);
  *(uint32_t*)(hb1 + (size_t)wid * ND + lane * 2) = o;
}

__global__ __launch_bounds__(256) void gather_h(
    const u16* __restrict__ H, const int* __restrict__ rowptr,
    const int* __restrict__ csr, u16* __restrict__ r2) {
  const int wid  = blockIdx.x * 4 + (threadIdx.x >> 6);
  const int lane = threadIdx.x & 63;
  if (wid >= MPAD) return;
  float acc[8];
#pragma unroll
  for (int j = 0; j < 8; ++j) acc[j] = 0.f;
  if (wid < NN) {
    bf16x8 v = *(const bf16x8*)(H + (size_t)wid * NH + lane * 8);
#pragma unroll
    for (int j = 0; j < 8; ++j) acc[j] = bf2f((u16)v[j]);
    const int beg = rowptr[wid], end = rowptr[wid + 1];
    int e = beg;
    for (; e + 1 < end; e += 2) {
      int s0 = csr[e], s1 = csr[e + 1];
      bf16x8 v0 = *(const bf16x8*)(H + (size_t)s0 * NH + lane * 8);
      bf16x8 v1 = *(const bf16x8*)(H + (size_t)s1 * NH + lane * 8);
#pragma unroll
      for (int j = 0; j < 8; ++j) acc[j] += bf2f((u16)v0[j]) + bf2f((u16)v1[j]);
    }
    if (e < end) {
      int s0 = csr[e];
      bf16x8 v0 = *(const bf16x8*)(H + (size_t)s0 * NH + lane * 8);
#pragma unroll
      for (int j = 0; j < 8; ++j) acc[j] += bf2f((u16)v0[j]);
    }
  }
  union { u16 u[8]; uint4 q; } o;
#pragma unroll
  for (int j = 0; j < 8; ++j) o.u[j] = f2bf(acc[j]);
  *(uint4*)(r2 + (size_t)wid * NH + lane * 8) = o.q;
}

// out[128] = ((s/NN) @ W2b + b2b) @ Wf + bf   (all f32)
__global__ void final_fuse(const float* __restrict__ s, const float* __restrict__ W2b,
                           const float* __restrict__ b2b, const float* __restrict__ Wf,
                           const float* __restrict__ bfv, float* __restrict__ out) {
  __shared__ float pooled[NH];
  const int j = threadIdx.x;
  const float invN = 1.0f / (float)NN;
  float acc = b2b[j];
  for (int k = 0; k < NH; ++k) acc += s[k] * invN * W2b[k * NH + j];
  pooled[j] = acc;
  __syncthreads();
  if (j < NO) {
    float o = bfv[j];
    for (int k = 0; k < NH; ++k) o += pooled[k] * Wf[k * NO + j];
    out[j] = o;
  }
}

__global__ void ws_sentinel(float* out) {
  if (threadIdx.x < NO) out[threadIdx.x] = -12345.0f;
}

extern "C" void kernel_launch(void* const* d_in, const int* in_sizes, int n_in,
                              void* d_out, int out_size, void* d_ws, size_t ws_size,
                              hipStream_t stream) {
  const float* x   = (const float*)d_in[0];
  const int*   ei  = (const int*)d_in[1];
  const float* W1a = (const float*)d_in[2];
  const float* b1a = (const float*)d_in[3];
  const float* W1b = (const float*)d_in[4];
  const float* b1b = (const float*)d_in[5];
  const float* W2a = (const float*)d_in[6];
  const float* b2a = (const float*)d_in[7];
  const float* W2b = (const float*)d_in[8];
  const float* b2b = (const float*)d_in[9];
  const float* Wf  = (const float*)d_in[10];
  const float* bfv = (const float*)d_in[11];
  float* out = (float*)d_out;

  const size_t HB1 = (size_t)MPAD * ND * 2;  // 12.8 MB bf16
  const size_t RB  = (size_t)MPAD * NH * 2;  // 51.25 MB bf16 (r1, then r2)
  const size_t HB  = (size_t)MPAD * NH * 2;  // 51.25 MB bf16 (h1)
  const size_t WB  = 2 * (size_t)NH * ND * 2 + 4 * (size_t)NH * NH * 2;
  const size_t CSRB = (size_t)(NN + 1) * 4 + 2 * (size_t)NN * 4 + (size_t)NE * 4
                      + 2 * (size_t)NB * 4;
  const size_t NEED = HB1 + RB + HB + WB + CSRB + NH * 4 + 32 * 256;
  if (ws_size < NEED) {
    ws_sentinel<<<1, 128, 0, stream>>>(out);
    return;
  }

  char* ws = (char*)d_ws;
  size_t off = 0;
  auto take = [&](size_t bytes) {
    char* p = ws + off;
    off = (off + bytes + 255) & ~(size_t)255;
    return p;
  };
  u16* hb1 = (u16*)take(HB1);
  u16* R   = (u16*)take(RB);
  u16* H   = (u16*)take(HB);
  u16* W1aT_hi = (u16*)take((size_t)NH * ND * 2);
  u16* W1aT_lo = (u16*)take((size_t)NH * ND * 2);
  u16* W1bT_hi = (u16*)take((size_t)NH * NH * 2);
  u16* W1bT_lo = (u16*)take((size_t)NH * NH * 2);
  u16* W2aT_hi = (u16*)take((size_t)NH * NH * 2);
  u16* W2aT_lo = (u16*)take((size_t)NH * NH * 2);
  int* deg    = (int*)take((size_t)NN * 4);
  int* cursor = (int*)take((size_t)NN * 4);
  int* rowptr = (int*)take((size_t)(NN + 1) * 4);
  int* csr    = (int*)take((size_t)NE * 4);
  int* bsum   = (int*)take((size_t)NB * 4);
  int* boff   = (int*)take((size_t)NB * 4);
  float* svec = (float*)take((size_t)NH * 4);

  hipMemsetAsync(svec, 0, NH * 4, stream);
  hipMemsetAsync(deg, 0, (size_t)NN * 4, stream);

  // weights -> transposed bf16 hi/lo
  cvtWT<<<(ND * NH + 255) / 256, 256, 0, stream>>>(W1a, W1aT_hi, W1aT_lo, ND, NH);
  cvtWT<<<(NH * NH + 255) / 256, 256, 0, stream>>>(W1b, W1bT_hi, W1bT_lo, NH, NH);
  cvtWT<<<(NH * NH + 255) / 256, 256, 0, stream>>>(W2a, W2aT_hi, W2aT_lo, NH, NH);

  // CSR: deg -> parallel exclusive scan -> rowptr/cursor -> csr
  hist_dst<<<(NE + 255) / 256, 256, 0, stream>>>(ei, deg);
  deg_partial<<<NB, 256, 0, stream>>>(deg, bsum);
  scan_bsum<<<1, 256, 0, stream>>>(bsum, boff, rowptr);
  scan_apply<<<NB, 256, 0, stream>>>(deg, boff, rowptr, cursor);
  fill_csr<<<(NE + 255) / 256, 256, 0, stream>>>(ei, cursor, csr);

  // conv1: gather + MLP
  gather_x<<<(MPAD + 3) / 4, 256, 0, stream>>>(x, rowptr, csr, hb1);
  gemm_bt<ND, 0><<<(MPAD / 128) * 4, 256, 0, stream>>>(hb1, W1aT_hi, W1aT_lo, b1a, R, nullptr);
  gemm_bt<NH, 1><<<(MPAD / 128) * 4, 256, 0, stream>>>(R, W1bT_hi, W1bT_lo, b1b, H, nullptr);

  // conv2: gather (r2 overwrites R) + first layer fused with relu+mean-pool
  gather_h<<<(MPAD + 3) / 4, 256, 0, stream>>>(H, rowptr, csr, R);
  gemm_bt<NH, 2><<<(MPAD / 128) * 4, 256, 0, stream>>>(R, W2aT_hi, W2aT_lo, b2a, nullptr, svec);

  // pooled @ W2b + b2b then @ Wf + bf
  final_fuse<<<1, NH, 0, stream>>>(svec, W2b, b2b, Wf, bfv, out);
}

// Round 7
// 364.634 us; speedup vs baseline: 14.5365x; 1.1149x over previous
//
#include <hip/hip_runtime.h>
#include <stdint.h>

#define NN 50000
#define NE 600000
#define ND 128
#define NH 512
#define NO 128
#define MPAD 50048  // 391 * 128
#define NB 196      // ceil(NN/256) scan blocks

typedef unsigned short u16;
typedef uint8_t u8;
typedef __attribute__((ext_vector_type(8))) short bf16x8;
typedef __attribute__((ext_vector_type(4))) float f32x4;
typedef __attribute__((ext_vector_type(2))) float f32x2;

__device__ __forceinline__ u16 f2bf(float f) {
  union { float f; uint32_t u; } v; v.f = f;
  uint32_t u = v.u;
  uint32_t r = (u + 0x7fffu + ((u >> 16) & 1u)) >> 16;
  return (u16)r;
}
__device__ __forceinline__ float bf2f(u16 h) {
  union { uint32_t u; float f; } v; v.u = ((uint32_t)h) << 16; return v.f;
}
__device__ __forceinline__ uint64_t f42bfq(float4 v) {
  union { u16 u[4]; uint64_t q; } o;
  o.u[0] = f2bf(v.x); o.u[1] = f2bf(v.y); o.u[2] = f2bf(v.z); o.u[3] = f2bf(v.w);
  return o.q;
}

// ---- fp8 e4m3 (OCP) encode/decode: HW cvt on gfx950, SW fallback ----
#if defined(__has_builtin)
#if __has_builtin(__builtin_amdgcn_cvt_pk_f32_fp8) && __has_builtin(__builtin_amdgcn_cvt_pk_fp8_f32)
#define HW_FP8 1
#endif
#endif
#ifndef HW_FP8
#define HW_FP8 0
#endif

__device__ __forceinline__ u8 f2fp8(float f) {
#if HW_FP8
  return (u8)(__builtin_amdgcn_cvt_pk_fp8_f32(f, f, 0, false) & 0xff);
#else
  union { float f; uint32_t u; } v; v.f = f;
  uint32_t s = v.u >> 31;
  float a = fabsf(f);
  if (a >= 448.f) return (u8)((s << 7) | 0x7e);
  if (a < 0.015625f) {                       // denormal region (< 2^-6)
    uint32_t m = (uint32_t)(a * 512.0f + 0.5f);
    if (m > 7) return (u8)((s << 7) | 8);    // rounded up to min normal
    return (u8)((s << 7) | m);
  }
  uint32_t u = v.u & 0x7fffffff;
  uint32_t r = u + 0x7FFFF + ((u >> 20) & 1);  // RNE at bit 20
  int e8 = (int)(r >> 23) - 120;
  if (e8 >= 16) return (u8)((s << 7) | 0x7e);
  return (u8)((s << 7) | ((uint32_t)e8 << 3) | ((r >> 20) & 7));
#endif
}

template<bool HI>
__device__ __forceinline__ f32x2 fp8x2_f32(uint32_t w) {
#if HW_FP8
  return __builtin_amdgcn_cvt_pk_f32_fp8((int)w, HI);
#else
  uint32_t h = HI ? (w >> 16) : w;
  f32x2 r;
  for (int i = 0; i < 2; ++i) {
    uint32_t b = (h >> (i * 8)) & 0xff;
    uint32_t s = (b >> 7) & 1, e = (b >> 3) & 15, m = b & 7;
    float t;
    if (e == 0) t = (float)m * 0.001953125f;
    else { union { uint32_t u; float f; } v; v.u = ((e + 120) << 23) | (m << 20); t = v.f; }
    r[i] = s ? -t : t;
  }
  return r;
#endif
}

__device__ __forceinline__ void gld16(const u16* g, u16* l) {
  __builtin_amdgcn_global_load_lds(
      (const __attribute__((address_space(1))) void*)g,
      (__attribute__((address_space(3))) void*)l, 16, 0, 0);
}

// ---------------------------------------------------------------------------
// GEMM: C[M,512] = A[M,K](bf16) @ B^T   B stored transposed [512,K], hi+lo
// 1-D grid, bijective XCD remap, m=wgid>>2 n=wgid&3 (A-tile L2 reuse).
// LDS tiles XOR-swizzled both-sides (pre-swizzled global src, same XOR on read).
// EPI 0: relu -> bf16 store ; EPI 1: plain -> fp8 store (H) ;
// EPI 2: relu -> guarded column-sum atomicAdd into sumOut[512]
// ---------------------------------------------------------------------------
template<int K, int EPI>
__global__ __launch_bounds__(256) void gemm_bt(
    const u16* __restrict__ A, const u16* __restrict__ Bhi,
    const u16* __restrict__ Blo, const float* __restrict__ bias,
    u16* __restrict__ outB, u8* __restrict__ outF8,
    float* __restrict__ sumOut)
{
  __shared__ u16 As[128 * 64];
  __shared__ u16 BsH[128 * 64];
  __shared__ u16 BsL[128 * 64];
  const int nwg  = gridDim.x;
  const int q    = nwg >> 3, r = nwg & 7;
  const int xcd  = blockIdx.x & 7, loc = blockIdx.x >> 3;
  const int wgid = (xcd < r ? xcd * (q + 1) : r * (q + 1) + (xcd - r) * q) + loc;
  const int m0   = (wgid >> 2) * 128;
  const int n0   = (wgid & 3) * 128;

  const int tid  = threadIdx.x;
  const int w    = tid >> 6;
  const int lane = tid & 63;
  const int wm   = (w >> 1) * 64;
  const int wn   = (w & 1) * 64;
  const int l15  = lane & 15;
  const int lh   = lane >> 4;

  const f32x4 z4 = {0.f, 0.f, 0.f, 0.f};
  f32x4 acc[4][4];
#pragma unroll
  for (int m = 0; m < 4; ++m)
#pragma unroll
    for (int n = 0; n < 4; ++n) acc[m][n] = z4;

  for (int k0 = 0; k0 < K; k0 += 64) {
#pragma unroll
    for (int i = 0; i < 4; ++i) {
      const int cc  = i * 256 + w * 64 + lane;     // 16B chunk id, lane-contig
      const int row = cc >> 3;
      const int csw = (cc ^ row) & 7;              // swizzled source chunk
      const int ldsbase = (i * 256 + w * 64) * 8;  // u16 units, wave-uniform (linear)
      gld16(A   + (size_t)(m0 + row) * K + k0 + csw * 8, As  + ldsbase);
      gld16(Bhi + (size_t)(n0 + row) * K + k0 + csw * 8, BsH + ldsbase);
      gld16(Blo + (size_t)(n0 + row) * K + k0 + csw * 8, BsL + ldsbase);
    }
    __syncthreads();
#pragma unroll
    for (int ks = 0; ks < 2; ++ks) {
      bf16x8 a[4], bh[4], bl[4];
#pragma unroll
      for (int m = 0; m < 4; ++m) {
        const int row = wm + m * 16 + l15;
        const int ch  = (ks * 4 + lh) ^ (row & 7);
        a[m] = *(const bf16x8*)&As[row * 64 + ch * 8];
      }
#pragma unroll
      for (int n = 0; n < 4; ++n) {
        const int row = wn + n * 16 + l15;
        const int ch  = (ks * 4 + lh) ^ (row & 7);
        bh[n] = *(const bf16x8*)&BsH[row * 64 + ch * 8];
        bl[n] = *(const bf16x8*)&BsL[row * 64 + ch * 8];
      }
#pragma unroll
      for (int m = 0; m < 4; ++m)
#pragma unroll
        for (int n = 0; n < 4; ++n) {
          acc[m][n] = __builtin_amdgcn_mfma_f32_16x16x32_bf16(a[m], bh[n], acc[m][n], 0, 0, 0);
          acc[m][n] = __builtin_amdgcn_mfma_f32_16x16x32_bf16(a[m], bl[n], acc[m][n], 0, 0, 0);
        }
    }
    __syncthreads();
  }

  if (EPI == 2) {
#pragma unroll
    for (int n = 0; n < 4; ++n) {
      const int gc = n0 + wn + n * 16 + l15;
      const float bv = bias[gc];
      float p = 0.f;
#pragma unroll
      for (int m = 0; m < 4; ++m) {
        const int rbase = m0 + wm + m * 16 + lh * 4;
#pragma unroll
        for (int j = 0; j < 4; ++j) {
          if (rbase + j < NN) p += fmaxf(acc[m][n][j] + bv, 0.f);
        }
      }
      p += __shfl_xor(p, 16);
      p += __shfl_xor(p, 32);
      if (lane < 16) atomicAdd(&sumOut[gc], p);
    }
  } else {
#pragma unroll
    for (int m = 0; m < 4; ++m) {
#pragma unroll
      for (int j = 0; j < 4; ++j) {
        const int gr = m0 + wm + m * 16 + lh * 4 + j;
#pragma unroll
        for (int n = 0; n < 4; ++n) {
          const int gc = n0 + wn + n * 16 + l15;
          const float v = acc[m][n][j] + bias[gc];
          if (EPI == 0) outB[(size_t)gr * NH + gc] = f2bf(fmaxf(v, 0.f));
          else          outF8[(size_t)gr * NH + gc] = f2fp8(v);
        }
      }
    }
  }
}

// f32 weight [Kd,Nd] -> transposed bf16 hi/lo [Nd,Kd]
__global__ void cvtWT(const float* __restrict__ W, u16* __restrict__ Thi,
                      u16* __restrict__ Tlo, int Kd, int Nd) {
  int t = blockIdx.x * 256 + threadIdx.x;
  if (t >= Kd * Nd) return;
  int k = t / Nd, n = t - k * Nd;
  float wv = W[t];
  u16 hi = f2bf(wv);
  float lo = wv - bf2f(hi);
  Thi[n * Kd + k] = hi;
  Tlo[n * Kd + k] = f2bf(lo);
}

// x f32 [NN][128] -> bf16 [MPAD][128] (pad rows zero); 4 cols/thread
__global__ void cvt_x(const float4* __restrict__ x4, uint64_t* __restrict__ xb) {
  int t = blockIdx.x * 256 + threadIdx.x;
  if (t >= MPAD * 32) return;
  int row = t >> 5;
  uint64_t qv = 0;
  if (row < NN) qv = f42bfq(x4[t]);
  xb[t] = qv;
}

// ---------------- CSR construction ----------------
__global__ void hist_dst(const int* __restrict__ ei, int* __restrict__ deg) {
  int e = blockIdx.x * 256 + threadIdx.x;
  if (e < NE) atomicAdd(&deg[ei[NE + e]], 1);
}

__global__ void deg_partial(const int* __restrict__ deg, int* __restrict__ bsum) {
  const int i = blockIdx.x * 256 + threadIdx.x;
  int v = (i < NN) ? deg[i] : 0;
#pragma unroll
  for (int o = 1; o < 64; o <<= 1) v += __shfl_xor(v, o);
  __shared__ int ws[4];
  if ((threadIdx.x & 63) == 0) ws[threadIdx.x >> 6] = v;
  __syncthreads();
  if (threadIdx.x == 0) bsum[blockIdx.x] = ws[0] + ws[1] + ws[2] + ws[3];
}

__global__ void scan_bsum(const int* __restrict__ bsum, int* __restrict__ boff,
                          int* __restrict__ rowptr) {
  __shared__ int s[256];
  const int t = threadIdx.x;
  int v = (t < NB) ? bsum[t] : 0;
  s[t] = v;
  __syncthreads();
  for (int o = 1; o < 256; o <<= 1) {
    int u = (t >= o) ? s[t - o] : 0;
    __syncthreads();
    s[t] += u;
    __syncthreads();
  }
  if (t < NB) boff[t] = s[t] - v;
  if (t == 0) rowptr[NN] = NE;
}

__global__ void scan_apply(const int* __restrict__ deg, const int* __restrict__ boff,
                           int* __restrict__ rowptr, int* __restrict__ cursor) {
  __shared__ int s[256];
  const int t = threadIdx.x;
  const int i = blockIdx.x * 256 + t;
  int v = (i < NN) ? deg[i] : 0;
  s[t] = v;
  __syncthreads();
  for (int o = 1; o < 256; o <<= 1) {
    int u = (t >= o) ? s[t - o] : 0;
    __syncthreads();
    s[t] += u;
    __syncthreads();
  }
  if (i < NN) {
    int ex = boff[blockIdx.x] + s[t] - v;
    rowptr[i] = ex;
    cursor[i] = ex;
  }
}

__global__ void fill_csr(const int* __restrict__ ei, int* __restrict__ cursor,
                         int* __restrict__ csr) {
  int e = blockIdx.x * 256 + threadIdx.x;
  if (e >= NE) return;
  int d = ei[NE + e];
  int p = atomicAdd(&cursor[d], 1);
  csr[p] = ei[e];
}

// ---------------- gather-reduce aggregations ----------------
// conv1: hb1[i][:] = bf16( xb[i][:] + sum_{e} xb[csr[e]][:] )  (xb bf16, dim 128)
__global__ __launch_bounds__(256) void gather_x(
    const u16* __restrict__ xb, const int* __restrict__ rowptr,
    const int* __restrict__ csr, u16* __restrict__ hb1) {
  const int wid  = blockIdx.x * 4 + (threadIdx.x >> 6);
  const int lane = threadIdx.x & 63;
  if (wid >= MPAD) return;
  float a0 = 0.f, a1 = 0.f;
  if (wid < NN) {
    uint32_t v = *(const uint32_t*)(xb + (size_t)wid * ND + lane * 2);
    a0 = bf2f((u16)v); a1 = bf2f((u16)(v >> 16));
    const int beg = rowptr[wid], end = rowptr[wid + 1];
    int e = beg;
    for (; e + 1 < end; e += 2) {
      int s0 = csr[e], s1 = csr[e + 1];
      uint32_t v0 = *(const uint32_t*)(xb + (size_t)s0 * ND + lane * 2);
      uint32_t v1 = *(const uint32_t*)(xb + (size_t)s1 * ND + lane * 2);
      a0 += bf2f((u16)v0) + bf2f((u16)v1);
      a1 += bf2f((u16)(v0 >> 16)) + bf2f((u16)(v1 >> 16));
    }
    if (e < end) {
      int s0 = csr[e];
      uint32_t v0 = *(const uint32_t*)(xb + (size_t)s0 * ND + lane * 2);
      a0 += bf2f((u16)v0);
      a1 += bf2f((u16)(v0 >> 16));
    }
  }
  uint32_t o = (uint32_t)f2bf(a0) | ((uint32_t)f2bf(a1) << 16);
  *(uint32_t*)(hb1 + (size_t)wid * ND + lane * 2) = o;
}

__device__ __forceinline__ void acc_fp8x8(float* acc, uint2 v) {
  f32x2 p;
  p = fp8x2_f32<false>(v.x); acc[0] += p.x; acc[1] += p.y;
  p = fp8x2_f32<true >(v.x); acc[2] += p.x; acc[3] += p.y;
  p = fp8x2_f32<false>(v.y); acc[4] += p.x; acc[5] += p.y;
  p = fp8x2_f32<true >(v.y); acc[6] += p.x; acc[7] += p.y;
}

// conv2: r2[i][:] = bf16( H8[i][:] + sum_{e} H8[csr[e]][:] )  (H8 fp8, dim 512)
__global__ __launch_bounds__(256) void gather_h(
    const u8* __restrict__ H8, const int* __restrict__ rowptr,
    const int* __restrict__ csr, u16* __restrict__ r2) {
  const int wid  = blockIdx.x * 4 + (threadIdx.x >> 6);
  const int lane = threadIdx.x & 63;
  if (wid >= MPAD) return;
  float acc[8];
#pragma unroll
  for (int j = 0; j < 8; ++j) acc[j] = 0.f;
  if (wid < NN) {
    acc_fp8x8(acc, *(const uint2*)(H8 + (size_t)wid * NH + lane * 8));
    const int beg = rowptr[wid], end = rowptr[wid + 1];
    int e = beg;
    for (; e + 1 < end; e += 2) {
      int s0 = csr[e], s1 = csr[e + 1];
      uint2 v0 = *(const uint2*)(H8 + (size_t)s0 * NH + lane * 8);
      uint2 v1 = *(const uint2*)(H8 + (size_t)s1 * NH + lane * 8);
      acc_fp8x8(acc, v0);
      acc_fp8x8(acc, v1);
    }
    if (e < end) {
      int s0 = csr[e];
      acc_fp8x8(acc, *(const uint2*)(H8 + (size_t)s0 * NH + lane * 8));
    }
  }
  union { u16 u[8]; uint4 q; } o;
#pragma unroll
  for (int j = 0; j < 8; ++j) o.u[j] = f2bf(acc[j]);
  *(uint4*)(r2 + (size_t)wid * NH + lane * 8) = o.q;
}

// out[128] = ((s/NN) @ W2b + b2b) @ Wf + bf   (all f32)
__global__ void final_fuse(const float* __restrict__ s, const float* __restrict__ W2b,
                           const float* __restrict__ b2b, const float* __restrict__ Wf,
                           const float* __restrict__ bfv, float* __restrict__ out) {
  __shared__ float pooled[NH];
  const int j = threadIdx.x;
  const float invN = 1.0f / (float)NN;
  float acc = b2b[j];
  for (int k = 0; k < NH; ++k) acc += s[k] * invN * W2b[k * NH + j];
  pooled[j] = acc;
  __syncthreads();
  if (j < NO) {
    float o = bfv[j];
    for (int k = 0; k < NH; ++k) o += pooled[k] * Wf[k * NO + j];
    out[j] = o;
  }
}

__global__ void ws_sentinel(float* out) {
  if (threadIdx.x < NO) out[threadIdx.x] = -12345.0f;
}

extern "C" void kernel_launch(void* const* d_in, const int* in_sizes, int n_in,
                              void* d_out, int out_size, void* d_ws, size_t ws_size,
                              hipStream_t stream) {
  const float* x   = (const float*)d_in[0];
  const int*   ei  = (const int*)d_in[1];
  const float* W1a = (const float*)d_in[2];
  const float* b1a = (const float*)d_in[3];
  const float* W1b = (const float*)d_in[4];
  const float* b1b = (const float*)d_in[5];
  const float* W2a = (const float*)d_in[6];
  const float* b2a = (const float*)d_in[7];
  const float* W2b = (const float*)d_in[8];
  const float* b2b = (const float*)d_in[9];
  const float* Wf  = (const float*)d_in[10];
  const float* bfv = (const float*)d_in[11];
  float* out = (float*)d_out;

  const size_t XB  = (size_t)MPAD * ND * 2;  // 12.8 MB bf16 x
  const size_t HB1 = (size_t)MPAD * ND * 2;  // 12.8 MB bf16 agg1
  const size_t RB  = (size_t)MPAD * NH * 2;  // 51.25 MB bf16 (r1, then r2)
  const size_t H8B = (size_t)MPAD * NH;      // 25.6 MB fp8 (h1)
  const size_t WB  = 2 * (size_t)NH * ND * 2 + 4 * (size_t)NH * NH * 2;
  const size_t CSRB = (size_t)(NN + 1) * 4 + 2 * (size_t)NN * 4 + (size_t)NE * 4
                      + 2 * (size_t)NB * 4;
  const size_t NEED = XB + HB1 + RB + H8B + WB + CSRB + NH * 4 + 32 * 256;
  if (ws_size < NEED) {
    ws_sentinel<<<1, 128, 0, stream>>>(out);
    return;
  }

  char* ws = (char*)d_ws;
  size_t off = 0;
  auto take = [&](size_t bytes) {
    char* p = ws + off;
    off = (off + bytes + 255) & ~(size_t)255;
    return p;
  };
  u16* xb  = (u16*)take(XB);
  u16* hb1 = (u16*)take(HB1);
  u16* R   = (u16*)take(RB);
  u8*  H8  = (u8*)take(H8B);
  u16* W1aT_hi = (u16*)take((size_t)NH * ND * 2);
  u16* W1aT_lo = (u16*)take((size_t)NH * ND * 2);
  u16* W1bT_hi = (u16*)take((size_t)NH * NH * 2);
  u16* W1bT_lo = (u16*)take((size_t)NH * NH * 2);
  u16* W2aT_hi = (u16*)take((size_t)NH * NH * 2);
  u16* W2aT_lo = (u16*)take((size_t)NH * NH * 2);
  int* deg    = (int*)take((size_t)NN * 4);
  int* cursor = (int*)take((size_t)NN * 4);
  int* rowptr = (int*)take((size_t)(NN + 1) * 4);
  int* csr    = (int*)take((size_t)NE * 4);
  int* bsum   = (int*)take((size_t)NB * 4);
  int* boff   = (int*)take((size_t)NB * 4);
  float* svec = (float*)take((size_t)NH * 4);

  (void)hipMemsetAsync(svec, 0, NH * 4, stream);
  (void)hipMemsetAsync(deg, 0, (size_t)NN * 4, stream);

  // weights -> transposed bf16 hi/lo; x -> bf16 padded
  cvtWT<<<(ND * NH + 255) / 256, 256, 0, stream>>>(W1a, W1aT_hi, W1aT_lo, ND, NH);
  cvtWT<<<(NH * NH + 255) / 256, 256, 0, stream>>>(W1b, W1bT_hi, W1bT_lo, NH, NH);
  cvtWT<<<(NH * NH + 255) / 256, 256, 0, stream>>>(W2a, W2aT_hi, W2aT_lo, NH, NH);
  cvt_x<<<(MPAD * 32 + 255) / 256, 256, 0, stream>>>((const float4*)x, (uint64_t*)xb);

  // CSR: deg -> parallel exclusive scan -> rowptr/cursor -> csr
  hist_dst<<<(NE + 255) / 256, 256, 0, stream>>>(ei, deg);
  deg_partial<<<NB, 256, 0, stream>>>(deg, bsum);
  scan_bsum<<<1, 256, 0, stream>>>(bsum, boff, rowptr);
  scan_apply<<<NB, 256, 0, stream>>>(deg, boff, rowptr, cursor);
  fill_csr<<<(NE + 255) / 256, 256, 0, stream>>>(ei, cursor, csr);

  // conv1: gather (bf16) + MLP; h1 stored fp8
  gather_x<<<(MPAD + 3) / 4, 256, 0, stream>>>(xb, rowptr, csr, hb1);
  gemm_bt<ND, 0><<<(MPAD / 128) * 4, 256, 0, stream>>>(hb1, W1aT_hi, W1aT_lo, b1a, R, nullptr, nullptr);
  gemm_bt<NH, 1><<<(MPAD / 128) * 4, 256, 0, stream>>>(R, W1bT_hi, W1bT_lo, b1b, nullptr, H8, nullptr);

  // conv2: gather fp8 (r2 overwrites R) + first layer fused with relu+mean-pool
  gather_h<<<(MPAD + 3) / 4, 256, 0, stream>>>(H8, rowptr, csr, R);
  gemm_bt<NH, 2><<<(MPAD / 128) * 4, 256, 0, stream>>>(R, W2aT_hi, W2aT_lo, b2a, nullptr, nullptr, svec);

  // pooled @ W2b + b2b then @ Wf + bf
  final_fuse<<<1, NH, 0, stream>>>(svec, W2b, b2b, Wf, bfv, out);
}